// Round 7
// baseline (260.947 us; speedup 1.0000x reference)
//
#include <hip/hip_runtime.h>
#include <stdint.h>

// MHA forward, B=8 T=1024 C=1024 H=16 D=64.
// cast3 -> QKV GEMM (128x256 tile, B streamed global->VGPR, A-only LDS dbuf;
// writes packed QK [stride 2048, Q pre-scaled] + V^T directly)
// -> flash attention -> proj GEMM (+bias, fp32). 4 launches.

#define Bn 8
#define Tn 1024
#define Cn 1024
#define Hn 16
#define Dn 64
#define Mn (Bn * Tn)      // 8192
#define NQKV (3 * Cn)     // 3072
#define QKS 2048          // packed QK row stride

typedef unsigned short u16;
typedef float f32x4 __attribute__((ext_vector_type(4)));
typedef __bf16 bf16x8 __attribute__((ext_vector_type(8)));
typedef unsigned short ushx8 __attribute__((ext_vector_type(8)));
typedef unsigned short ushx4 __attribute__((ext_vector_type(4)));

__device__ __forceinline__ u16 f2bf(float f) {
  unsigned int u = __float_as_uint(f);
  u += 0x7fffu + ((u >> 16) & 1u);   // RTN-even
  return (u16)(u >> 16);
}
__device__ __forceinline__ u16 f2bf_rna(float f) {
  return (u16)((__float_as_uint(f) + 0x8000u) >> 16);
}

__device__ __forceinline__ f32x4 mfma_bf16(ushx8 a, ushx8 b, f32x4 c) {
  return __builtin_amdgcn_mfma_f32_16x16x32_bf16(
      __builtin_bit_cast(bf16x8, a), __builtin_bit_cast(bf16x8, b), c, 0, 0, 0);
}

// async global->LDS, 16B per lane; LDS dest = wave-uniform base + lane*16 (m104)
__device__ __forceinline__ void async16(const u16* g, u16* l) {
  __builtin_amdgcn_global_load_lds(
      (__attribute__((address_space(1))) void*)(void*)g,
      (__attribute__((address_space(3))) void*)l, 16, 0, 0);
}

// ---- DPP 16-lane butterfly reductions (VALU-rate, no LDS pipe) ----
template <int CTRL>
__device__ __forceinline__ float dppmov(float v) {
  return __builtin_bit_cast(float, __builtin_amdgcn_update_dpp(
      0, __builtin_bit_cast(int, v), CTRL, 0xf, 0xf, true));
}
__device__ __forceinline__ float red16max(float v) {
  v = fmaxf(v, dppmov<0xB1>(v));
  v = fmaxf(v, dppmov<0x4E>(v));
  v = fmaxf(v, dppmov<0x141>(v));
  v = fmaxf(v, dppmov<0x140>(v));
  return v;
}
__device__ __forceinline__ float red16sum(float v) {
  v += dppmov<0xB1>(v);
  v += dppmov<0x4E>(v);
  v += dppmov<0x141>(v);
  v += dppmov<0x140>(v);
  return v;
}

// ---------------- fused cast fp32 -> bf16 (3 tensors, 1 launch) ----------------
__global__ void cast3_kernel(const float* __restrict__ a, u16* __restrict__ oa, int na4,
                             const float* __restrict__ b, u16* __restrict__ ob, int nb4,
                             const float* __restrict__ c, u16* __restrict__ oc, int nc4) {
  int i = blockIdx.x * blockDim.x + threadIdx.x;
  const float* in;
  u16* out;
  if (i < na4) { in = a; out = oa; }
  else if (i < na4 + nb4) { in = b; out = ob; i -= na4; }
  else if (i < na4 + nb4 + nc4) { in = c; out = oc; i -= na4 + nb4; }
  else return;
  float4 v = ((const float4*)in)[i];
  ushx4 o = { f2bf(v.x), f2bf(v.y), f2bf(v.z), f2bf(v.w) };
  ((ushx4*)out)[i] = o;
}

// ---------------- GEMM: C[m,n] = sum_k A[m,k]*Bw[n,k] ----------------
// 128m x 256n block, 4 waves; wave wv owns ALL 128 m x 64 n (n = wv*64..+64).
// A staged in LDS (dbuf, async DMA); B streamed global->VGPR per wave
// (B-frag n=l16,k=quad*8+j is exactly one dwordx4), register-double-buffered.
// LDS bytes/MFMA = 256 (vs 512 for the 2x2-wave layout) -> not LDS-BW-bound.
// QKV=1: cols [0,2048)->packed QK (stride 2048, Q scaled); [2048,3072)->V^T.
// QKV=0: fp32 out + bias.
#define SLOG2E 0.18033688011112042f
template <int QKV>
__global__ __launch_bounds__(256, 2) void gemm_bt(
    const u16* __restrict__ A, const u16* __restrict__ Bw,
    void* __restrict__ Cout, u16* __restrict__ vt,
    const float* __restrict__ bias, int N, int K) {
  __shared__ alignas(16) u16 As[2][128 * 32];   // 16 KB total

  const int tid = threadIdx.x;
  const int lane = tid & 63;
  const int wv = tid >> 6;
  const int quad = lane >> 4;
  const int l16 = lane & 15;
  const int m0 = blockIdx.x * 128;
  const int n0 = blockIdx.y * 256;
  const int wn = wv * 64;

  f32x4 acc[8][4];
#pragma unroll
  for (int i = 0; i < 8; ++i)
#pragma unroll
    for (int j = 0; j < 4; ++j) acc[i][j] = (f32x4){0.f, 0.f, 0.f, 0.f};

  // A staging: 512 chunks of 16B; call c covers chunk c*256+tid (lane-contig)
  const int r0 = tid >> 2;
  const int cc0 = tid & 3;
  const int gkc0 = cc0 ^ ((r0 >> 1) & 3);
  const int r1 = r0 + 64;
  const int gkc1 = cc0 ^ ((r1 >> 1) & 3);
  const u16* gA0 = A + (size_t)(m0 + r0) * K + gkc0 * 8;
  const u16* gA1 = A + (size_t)(m0 + r1) * K + gkc1 * 8;

  // A-fragment LDS offsets (swizzled slots)
  int aoff[8];
#pragma unroll
  for (int mi = 0; mi < 8; ++mi) {
    int ra = mi * 16 + l16;
    aoff[mi] = ra * 32 + (quad ^ ((ra >> 1) & 3)) * 8;
  }

  // B-fragment global pointers: frag(ni) at row n0+wn+ni*16+l16, k quad*8
  const u16* gB[4];
#pragma unroll
  for (int ni = 0; ni < 4; ++ni)
    gB[ni] = Bw + (size_t)(n0 + wn + ni * 16 + l16) * K + quad * 8;

  ushx8 bcur[4], bnxt[4];
#pragma unroll
  for (int ni = 0; ni < 4; ++ni) bcur[ni] = *(const ushx8*)gB[ni];

  // prefetch A epoch 0 -> buf 0
  async16(gA0, As[0] + tid * 8);
  async16(gA1, As[0] + (256 + tid) * 8);

  const int nep = K >> 5;
#pragma unroll 1
  for (int e = 0; e < nep; ++e) {
    const int k0 = e * 32;
    __syncthreads();   // drains DMA for As[e&1] (and in-flight bnxt, which had a full epoch)

    if (e + 1 < nep) {
      u16* dst = As[(e + 1) & 1];
      async16(gA0 + k0 + 32, dst + tid * 8);
      async16(gA1 + k0 + 32, dst + (256 + tid) * 8);
#pragma unroll
      for (int ni = 0; ni < 4; ++ni)
        bnxt[ni] = *(const ushx8*)(gB[ni] + k0 + 32);
    }

    const u16* as = As[e & 1];
    ushx8 af[8];
#pragma unroll
    for (int mi = 0; mi < 8; ++mi) af[mi] = *(const ushx8*)(as + aoff[mi]);
#pragma unroll
    for (int mi = 0; mi < 8; ++mi)
#pragma unroll
      for (int ni = 0; ni < 4; ++ni)
        acc[mi][ni] = mfma_bf16(af[mi], bcur[ni], acc[mi][ni]);

    if (e + 1 < nep) {
#pragma unroll
      for (int ni = 0; ni < 4; ++ni) bcur[ni] = bnxt[ni];
    }
  }

  if constexpr (QKV) {
    if (n0 < 2 * Cn) {
      // packed QK buffer, stride 2048; scale Q cols (block-uniform: 256|1024)
      const float sc = (n0 < Cn) ? SLOG2E : 1.f;
#pragma unroll
      for (int mi = 0; mi < 8; ++mi) {
#pragma unroll
        for (int ni = 0; ni < 4; ++ni) {
          int col = n0 + wn + ni * 16 + l16;
#pragma unroll
          for (int i = 0; i < 4; ++i) {
            int row = m0 + mi * 16 + quad * 4 + i;
            ((u16*)Cout)[(size_t)row * QKS + col] = f2bf(acc[mi][ni][i] * sc);
          }
        }
      }
    } else {
      // V^T: lane's regs i=0..3 are consecutive t -> one 8B packed store
#pragma unroll
      for (int mi = 0; mi < 8; ++mi) {
#pragma unroll
        for (int ni = 0; ni < 4; ++ni) {
          int colV = n0 + wn + ni * 16 + l16 - 2 * Cn;  // 0..1023
          int hh = colV >> 6, dd = colV & 63;
          int row0 = m0 + mi * 16 + quad * 4;
          int bb = row0 >> 10, tt = row0 & 1023;
          unsigned int lo = (unsigned int)f2bf(acc[mi][ni][0]) |
                            ((unsigned int)f2bf(acc[mi][ni][1]) << 16);
          unsigned int hi = (unsigned int)f2bf(acc[mi][ni][2]) |
                            ((unsigned int)f2bf(acc[mi][ni][3]) << 16);
          uint2 pk = {lo, hi};
          *(uint2*)&vt[((size_t)(bb * Hn + hh) * Dn + dd) * Tn + tt] = pk;
        }
      }
    }
  } else {
#pragma unroll
    for (int mi = 0; mi < 8; ++mi) {
#pragma unroll
      for (int ni = 0; ni < 4; ++ni) {
        int col = n0 + wn + ni * 16 + l16;
        float bv = bias[col];
#pragma unroll
        for (int i = 0; i < 4; ++i) {
          int row = m0 + mi * 16 + quad * 4 + i;
          ((float*)Cout)[(size_t)row * N + col] = acc[mi][ni][i] + bv;
        }
      }
    }
  }
}

// ---------------- flash attention ----------------
// 1024 blocks (8,16,8); block j does 64-row q-tiles j and 15-j (17 kv-tiles —
// perfectly balanced). 3 blocks/CU. Wave wv owns q rows [wv*16, wv*16+16).
// Double-buffered async K/V^T staging; DPP reductions; raw v_exp_f32;
// Q pre-scaled in QKV GEMM (S already in log2 domain). QK stride = 2048.
__global__ __launch_bounds__(256, 3) void attn_kernel(
    const u16* __restrict__ qk, const u16* __restrict__ vt,
    u16* __restrict__ out) {
  const int j = blockIdx.x, h = blockIdx.y, b = blockIdx.z;
  const int tid = threadIdx.x;
  const int lane = tid & 63;
  const int wv = tid >> 6;
  const int quad = lane >> 4;
  const int l16 = lane & 15;

  __shared__ alignas(16) u16 Ks[2][64 * 64];   // [buf][kv][d] XOR-swizzled
  __shared__ alignas(16) u16 Vts[2][64 * 64];  // [buf][d][kv] XOR-swizzled
  __shared__ alignas(16) u16 Ps[4][16 * 72];   // per-wave P

  const u16* qb = qk + (size_t)b * Tn * QKS + h * Dn;
  const u16* kb = qk + (size_t)b * Tn * QKS + Cn + h * Dn;
  const u16* vtb = vt + (size_t)(b * Hn + h) * Dn * Tn;

  const int srow = tid >> 3;  // 0..31
  const int scc = tid & 7;
  u16* pswv = Ps[wv];

#pragma unroll 1
  for (int ph = 0; ph < 2; ++ph) {
    const int qt = ph ? (15 - j) : j;
    const int q0 = qt * 64;
    const int ntiles = qt + 1;

    // Q fragments (A-operand: m=l16, k=quad*8+jj); already scaled by SLOG2E
    ushx8 qf[2];
    {
      const u16* qp = qb + (size_t)(q0 + wv * 16 + l16) * QKS + quad * 8;
      qf[0] = *(const ushx8*)qp;
      qf[1] = *(const ushx8*)(qp + 32);
    }

    f32x4 o[4];
#pragma unroll
    for (int nt = 0; nt < 4; ++nt) o[nt] = (f32x4){0.f, 0.f, 0.f, 0.f};
    float mrow[4], lrow[4];
#pragma unroll
    for (int i = 0; i < 4; ++i) { mrow[i] = -__builtin_inff(); lrow[i] = 0.f; }

    __syncthreads();  // previous phase's compute done before overwriting buf0

    // prefetch tile 0 -> buf 0
#pragma unroll
    for (int c = 0; c < 2; ++c) {
      const int row = c * 32 + srow;
      const int gc = scc ^ (row & 7);
      async16(kb + (size_t)row * QKS + gc * 8, Ks[0] + (c * 256 + tid) * 8);
      async16(vtb + (size_t)row * Tn + gc * 8, Vts[0] + (c * 256 + tid) * 8);
    }

#pragma unroll 1
    for (int t = 0; t < ntiles; ++t) {
      const int kv0 = t * 64;
      const int bi = t & 1;
      __syncthreads();  // drains DMA for buf[bi]; all waves done with buf[bi^1]

      if (t + 1 < ntiles) {
        const int nkv0 = kv0 + 64;
        u16* kd = Ks[bi ^ 1];
        u16* vd = Vts[bi ^ 1];
#pragma unroll
        for (int c = 0; c < 2; ++c) {
          const int row = c * 32 + srow;
          const int gc = scc ^ (row & 7);
          async16(kb + (size_t)(nkv0 + row) * QKS + gc * 8, kd + (c * 256 + tid) * 8);
          async16(vtb + (size_t)row * Tn + nkv0 + gc * 8, vd + (c * 256 + tid) * 8);
        }
      }

      // S = Q K^T (already log2-scaled via Q)
      const u16* ks = Ks[bi];
      const u16* vs = Vts[bi];
      f32x4 s[4];
#pragma unroll
      for (int nt = 0; nt < 4; ++nt) s[nt] = (f32x4){0.f, 0.f, 0.f, 0.f};
#pragma unroll
      for (int nt = 0; nt < 4; ++nt) {
        const int rb = nt * 16 + l16;
        ushx8 b0 = *(const ushx8*)(ks + rb * 64 + (quad ^ (rb & 7)) * 8);
        ushx8 b1 = *(const ushx8*)(ks + rb * 64 + ((quad + 4) ^ (rb & 7)) * 8);
        s[nt] = mfma_bf16(qf[0], b0, s[nt]);
        s[nt] = mfma_bf16(qf[1], b1, s[nt]);
      }

      // online softmax (log2 domain), DPP reductions, raw v_exp_f32
      const bool dz = (kv0 + 64 > q0 + wv * 16);
#pragma unroll
      for (int i = 0; i < 4; ++i) {
        const int qr = q0 + wv * 16 + quad * 4 + i;
        float vv[4];
        float rmax = -__builtin_inff();
#pragma unroll
        for (int nt = 0; nt < 4; ++nt) {
          float v = s[nt][i];
          if (dz && (kv0 + nt * 16 + l16) > qr) v = -__builtin_inff();
          vv[nt] = v;
          rmax = fmaxf(rmax, v);
        }
        rmax = red16max(rmax);
        const float mnew = fmaxf(mrow[i], rmax);
        const float al = __builtin_amdgcn_exp2f(mrow[i] - mnew);
        mrow[i] = mnew;
        float rsum = 0.f;
#pragma unroll
        for (int nt = 0; nt < 4; ++nt) {
          float p = __builtin_amdgcn_exp2f(vv[nt] - mnew);
          rsum += p;
          pswv[(quad * 4 + i) * 72 + nt * 16 + l16] = f2bf_rna(p);
        }
        rsum = red16sum(rsum);
        lrow[i] = lrow[i] * al + rsum;
#pragma unroll
        for (int nt = 0; nt < 4; ++nt) o[nt][i] *= al;
      }

      // P A-fragments from wave-local LDS (DS in-order per wave, no barrier)
      ushx8 pf0, pf1;
      {
        const u16* pp = pswv + l16 * 72 + quad * 8;
        pf0 = *(const ushx8*)pp;
        pf1 = *(const ushx8*)(pp + 32);
      }

      // O += P V
#pragma unroll
      for (int nt = 0; nt < 4; ++nt) {
        const int rb = nt * 16 + l16;
        ushx8 v0 = *(const ushx8*)(vs + rb * 64 + (quad ^ (rb & 7)) * 8);
        ushx8 v1 = *(const ushx8*)(vs + rb * 64 + ((quad + 4) ^ (rb & 7)) * 8);
        o[nt] = mfma_bf16(pf0, v0, o[nt]);
        o[nt] = mfma_bf16(pf1, v1, o[nt]);
      }
    }

    // O/l, write y_attn as (B,T,C) bf16
#pragma unroll
    for (int i = 0; i < 4; ++i) {
      const float inv = 1.f / lrow[i];
      const int t = q0 + wv * 16 + quad * 4 + i;
      u16* op = out + ((size_t)(b * Tn + t)) * Cn + h * Dn + l16;
#pragma unroll
      for (int nt = 0; nt < 4; ++nt) op[nt * 16] = f2bf(o[nt][i] * inv);
    }
  }
}

// ---------------- launch ----------------
extern "C" void kernel_launch(void* const* d_in, const int* in_sizes, int n_in,
                              void* d_out, int out_size, void* d_ws, size_t ws_size,
                              hipStream_t stream) {
  const float* x = (const float*)d_in[0];
  const float* w_qkv = (const float*)d_in[1];
  const float* w_proj = (const float*)d_in[2];
  const float* b_proj = (const float*)d_in[3];
  float* out = (float*)d_out;
  char* ws = (char*)d_ws;

  u16* xb     = (u16*)(ws);                 // 16 MiB @ 0
  u16* wqkvb  = (u16*)(ws + 16777216);      //  6 MiB @ 16
  u16* wprojb = (u16*)(ws + 23068672);      //  2 MiB @ 22
  u16* qkb    = (u16*)(ws + 25165824);      // 32 MiB @ 24  (packed QK, stride 2048)
  u16* vtb    = (u16*)(ws + 58720256);      // 16 MiB @ 56
  u16* yb     = (u16*)(ws + 75497472);      // 16 MiB @ 72  (ends 88 MiB)

  cast3_kernel<<<12288, 256, 0, stream>>>(x, xb, 2097152,
                                          w_qkv, wqkvb, 786432,
                                          w_proj, wprojb, 262144);

  gemm_bt<1><<<dim3(Mn / 128, NQKV / 256), 256, 0, stream>>>(
      xb, wqkvb, (void*)qkb, vtb, nullptr, NQKV, Cn);

  attn_kernel<<<dim3(8, Hn, Bn), 256, 0, stream>>>(qkb, vtb, yb);

  gemm_bt<0><<<dim3(Mn / 128, Cn / 256), 256, 0, stream>>>(
      yb, wprojb, (void*)out, nullptr, b_proj, Cn, Cn);
}

// Round 8
// 249.530 us; speedup vs baseline: 1.0458x; 1.0458x over previous
//
#include <hip/hip_runtime.h>
#include <stdint.h>

// MHA forward, B=8 T=1024 C=1024 H=16 D=64.
// cast3 -> QKV GEMM (128x128 tile, 2x2 waves, dbuf LDS, 1 barrier/epoch;
// writes packed QK [stride 2048, Q pre-scaled] + V^T directly)
// -> flash attention -> proj GEMM (+bias, fp32). 4 launches.

#define Bn 8
#define Tn 1024
#define Cn 1024
#define Hn 16
#define Dn 64
#define Mn (Bn * Tn)      // 8192
#define NQKV (3 * Cn)     // 3072
#define QKS 2048          // packed QK row stride

typedef unsigned short u16;
typedef float f32x4 __attribute__((ext_vector_type(4)));
typedef __bf16 bf16x8 __attribute__((ext_vector_type(8)));
typedef unsigned short ushx8 __attribute__((ext_vector_type(8)));
typedef unsigned short ushx4 __attribute__((ext_vector_type(4)));

__device__ __forceinline__ u16 f2bf(float f) {
  unsigned int u = __float_as_uint(f);
  u += 0x7fffu + ((u >> 16) & 1u);   // RTN-even
  return (u16)(u >> 16);
}
__device__ __forceinline__ u16 f2bf_rna(float f) {
  return (u16)((__float_as_uint(f) + 0x8000u) >> 16);
}

__device__ __forceinline__ f32x4 mfma_bf16(ushx8 a, ushx8 b, f32x4 c) {
  return __builtin_amdgcn_mfma_f32_16x16x32_bf16(
      __builtin_bit_cast(bf16x8, a), __builtin_bit_cast(bf16x8, b), c, 0, 0, 0);
}

// async global->LDS, 16B per lane; LDS dest = wave-uniform base + lane*16 (m104)
__device__ __forceinline__ void async16(const u16* g, u16* l) {
  __builtin_amdgcn_global_load_lds(
      (__attribute__((address_space(1))) void*)(void*)g,
      (__attribute__((address_space(3))) void*)l, 16, 0, 0);
}

// ---- DPP 16-lane butterfly reductions (VALU-rate, no LDS pipe) ----
template <int CTRL>
__device__ __forceinline__ float dppmov(float v) {
  return __builtin_bit_cast(float, __builtin_amdgcn_update_dpp(
      0, __builtin_bit_cast(int, v), CTRL, 0xf, 0xf, true));
}
__device__ __forceinline__ float red16max(float v) {
  v = fmaxf(v, dppmov<0xB1>(v));
  v = fmaxf(v, dppmov<0x4E>(v));
  v = fmaxf(v, dppmov<0x141>(v));
  v = fmaxf(v, dppmov<0x140>(v));
  return v;
}
__device__ __forceinline__ float red16sum(float v) {
  v += dppmov<0xB1>(v);
  v += dppmov<0x4E>(v);
  v += dppmov<0x141>(v);
  v += dppmov<0x140>(v);
  return v;
}

// ---------------- fused cast fp32 -> bf16 (3 tensors, 1 launch) ----------------
__global__ void cast3_kernel(const float* __restrict__ a, u16* __restrict__ oa, int na4,
                             const float* __restrict__ b, u16* __restrict__ ob, int nb4,
                             const float* __restrict__ c, u16* __restrict__ oc, int nc4) {
  int i = blockIdx.x * blockDim.x + threadIdx.x;
  const float* in;
  u16* out;
  if (i < na4) { in = a; out = oa; }
  else if (i < na4 + nb4) { in = b; out = ob; i -= na4; }
  else if (i < na4 + nb4 + nc4) { in = c; out = oc; i -= na4 + nb4; }
  else return;
  float4 v = ((const float4*)in)[i];
  ushx4 o = { f2bf(v.x), f2bf(v.y), f2bf(v.z), f2bf(v.w) };
  ((ushx4*)out)[i] = o;
}

// ---------------- GEMM: C[m,n] = sum_k A[m,k]*Bw[n,k] ----------------
// 128x128 block, 2x2 waves (64x64 each), BK=32, shared LDS staging for A and B,
// DOUBLE-buffered -> single barrier per epoch (round-6 had two).
// QKV=1: cols [0,2048)->packed QK (stride 2048, Q cols scaled); [2048,3072)->V^T.
// QKV=0: fp32 out + bias.
#define SLOG2E 0.18033688011112042f
template <int QKV>
__global__ __launch_bounds__(256, 4) void gemm_bt(
    const u16* __restrict__ A, const u16* __restrict__ Bw,
    void* __restrict__ Cout, u16* __restrict__ vt,
    const float* __restrict__ bias, int N, int K) {
  __shared__ alignas(16) u16 As[2][128 * 32];   // 16 KB
  __shared__ alignas(16) u16 Bs[2][128 * 32];   // 16 KB

  const int tid = threadIdx.x;
  const int lane = tid & 63;
  const int wv = tid >> 6;
  const int quad = lane >> 4;
  const int l16 = lane & 15;
  const int m0 = blockIdx.x * 128;
  const int n0 = blockIdx.y * 128;
  const int wm = (wv >> 1) * 64;
  const int wn = (wv & 1) * 64;

  f32x4 acc[4][4];
#pragma unroll
  for (int i = 0; i < 4; ++i)
#pragma unroll
    for (int j = 0; j < 4; ++j) acc[i][j] = (f32x4){0.f, 0.f, 0.f, 0.f};

  // staging geometry: chunk idx = call*256 + tid; row = idx>>2, cc = idx&3.
  // Global k-chunk XOR-swizzled by row bits 1:2 (slot order fixed by DMA).
  const int r0 = tid >> 2;
  const int cc0 = tid & 3;
  const int gkc0 = cc0 ^ ((r0 >> 1) & 3);
  const int r1 = r0 + 64;
  const int gkc1 = cc0 ^ ((r1 >> 1) & 3);
  const u16* gA0 = A + (size_t)(m0 + r0) * K + gkc0 * 8;
  const u16* gA1 = A + (size_t)(m0 + r1) * K + gkc1 * 8;
  const u16* gB0 = Bw + (size_t)(n0 + r0) * K + gkc0 * 8;
  const u16* gB1 = Bw + (size_t)(n0 + r1) * K + gkc1 * 8;

  // fragment LDS offsets (swizzled slots)
  int aoff[4], boff[4];
#pragma unroll
  for (int mi = 0; mi < 4; ++mi) {
    int ra = wm + mi * 16 + l16;
    aoff[mi] = ra * 32 + (quad ^ ((ra >> 1) & 3)) * 8;
    int rb = wn + mi * 16 + l16;
    boff[mi] = rb * 32 + (quad ^ ((rb >> 1) & 3)) * 8;
  }

  // prefetch epoch 0 -> buf 0
  async16(gA0, As[0] + tid * 8);
  async16(gA1, As[0] + (256 + tid) * 8);
  async16(gB0, Bs[0] + tid * 8);
  async16(gB1, Bs[0] + (256 + tid) * 8);

  const int nep = K >> 5;
#pragma unroll 1
  for (int e = 0; e < nep; ++e) {
    const int bi = e & 1;
    __syncthreads();  // drains DMA for buf[bi]; all waves done reading buf[bi^1]

    if (e + 1 < nep) {
      const int k1 = (e + 1) * 32;
      u16* ad = As[bi ^ 1];
      u16* bd = Bs[bi ^ 1];
      async16(gA0 + k1, ad + tid * 8);
      async16(gA1 + k1, ad + (256 + tid) * 8);
      async16(gB0 + k1, bd + tid * 8);
      async16(gB1 + k1, bd + (256 + tid) * 8);
    }

    const u16* as = As[bi];
    const u16* bs = Bs[bi];
    ushx8 af[4], bf[4];
#pragma unroll
    for (int i = 0; i < 4; ++i) {
      af[i] = *(const ushx8*)(as + aoff[i]);
      bf[i] = *(const ushx8*)(bs + boff[i]);
    }
#pragma unroll
    for (int mi = 0; mi < 4; ++mi)
#pragma unroll
      for (int ni = 0; ni < 4; ++ni)
        acc[mi][ni] = mfma_bf16(af[mi], bf[ni], acc[mi][ni]);
  }

  if constexpr (QKV) {
    if (n0 < 2 * Cn) {
      // packed QK buffer, stride 2048; scale Q cols (block-uniform: 128 | 1024)
      const float sc = (n0 < Cn) ? SLOG2E : 1.f;
#pragma unroll
      for (int mi = 0; mi < 4; ++mi) {
#pragma unroll
        for (int ni = 0; ni < 4; ++ni) {
          int col = n0 + wn + ni * 16 + l16;
#pragma unroll
          for (int i = 0; i < 4; ++i) {
            int row = m0 + wm + mi * 16 + quad * 4 + i;
            ((u16*)Cout)[(size_t)row * QKS + col] = f2bf(acc[mi][ni][i] * sc);
          }
        }
      }
    } else {
      // V^T: lane's regs i=0..3 are consecutive t -> one 8B packed store
#pragma unroll
      for (int mi = 0; mi < 4; ++mi) {
#pragma unroll
        for (int ni = 0; ni < 4; ++ni) {
          int colV = n0 + wn + ni * 16 + l16 - 2 * Cn;  // 0..1023
          int hh = colV >> 6, dd = colV & 63;
          int row0 = m0 + wm + mi * 16 + quad * 4;
          int bb = row0 >> 10, tt = row0 & 1023;
          unsigned int lo = (unsigned int)f2bf(acc[mi][ni][0]) |
                            ((unsigned int)f2bf(acc[mi][ni][1]) << 16);
          unsigned int hi = (unsigned int)f2bf(acc[mi][ni][2]) |
                            ((unsigned int)f2bf(acc[mi][ni][3]) << 16);
          uint2 pk = {lo, hi};
          *(uint2*)&vt[((size_t)(bb * Hn + hh) * Dn + dd) * Tn + tt] = pk;
        }
      }
    }
  } else {
#pragma unroll
    for (int mi = 0; mi < 4; ++mi) {
#pragma unroll
      for (int ni = 0; ni < 4; ++ni) {
        int col = n0 + wn + ni * 16 + l16;
        float bv = bias[col];
#pragma unroll
        for (int i = 0; i < 4; ++i) {
          int row = m0 + wm + mi * 16 + quad * 4 + i;
          ((float*)Cout)[(size_t)row * N + col] = acc[mi][ni][i] + bv;
        }
      }
    }
  }
}

// ---------------- flash attention ----------------
// 1024 blocks (8,16,8); block j does 64-row q-tiles j and 15-j (17 kv-tiles —
// perfectly balanced). 3 blocks/CU. Wave wv owns q rows [wv*16, wv*16+16).
// Double-buffered async K/V^T staging; DPP reductions; raw v_exp_f32;
// Q pre-scaled in QKV GEMM (S already in log2 domain). QK stride = 2048.
__global__ __launch_bounds__(256, 3) void attn_kernel(
    const u16* __restrict__ qk, const u16* __restrict__ vt,
    u16* __restrict__ out) {
  const int j = blockIdx.x, h = blockIdx.y, b = blockIdx.z;
  const int tid = threadIdx.x;
  const int lane = tid & 63;
  const int wv = tid >> 6;
  const int quad = lane >> 4;
  const int l16 = lane & 15;

  __shared__ alignas(16) u16 Ks[2][64 * 64];   // [buf][kv][d] XOR-swizzled
  __shared__ alignas(16) u16 Vts[2][64 * 64];  // [buf][d][kv] XOR-swizzled
  __shared__ alignas(16) u16 Ps[4][16 * 72];   // per-wave P

  const u16* qb = qk + (size_t)b * Tn * QKS + h * Dn;
  const u16* kb = qk + (size_t)b * Tn * QKS + Cn + h * Dn;
  const u16* vtb = vt + (size_t)(b * Hn + h) * Dn * Tn;

  const int srow = tid >> 3;  // 0..31
  const int scc = tid & 7;
  u16* pswv = Ps[wv];

#pragma unroll 1
  for (int ph = 0; ph < 2; ++ph) {
    const int qt = ph ? (15 - j) : j;
    const int q0 = qt * 64;
    const int ntiles = qt + 1;

    // Q fragments (A-operand: m=l16, k=quad*8+jj); already scaled by SLOG2E
    ushx8 qf[2];
    {
      const u16* qp = qb + (size_t)(q0 + wv * 16 + l16) * QKS + quad * 8;
      qf[0] = *(const ushx8*)qp;
      qf[1] = *(const ushx8*)(qp + 32);
    }

    f32x4 o[4];
#pragma unroll
    for (int nt = 0; nt < 4; ++nt) o[nt] = (f32x4){0.f, 0.f, 0.f, 0.f};
    float mrow[4], lrow[4];
#pragma unroll
    for (int i = 0; i < 4; ++i) { mrow[i] = -__builtin_inff(); lrow[i] = 0.f; }

    __syncthreads();  // previous phase's compute done before overwriting buf0

    // prefetch tile 0 -> buf 0
#pragma unroll
    for (int c = 0; c < 2; ++c) {
      const int row = c * 32 + srow;
      const int gc = scc ^ (row & 7);
      async16(kb + (size_t)row * QKS + gc * 8, Ks[0] + (c * 256 + tid) * 8);
      async16(vtb + (size_t)row * Tn + gc * 8, Vts[0] + (c * 256 + tid) * 8);
    }

#pragma unroll 1
    for (int t = 0; t < ntiles; ++t) {
      const int kv0 = t * 64;
      const int bi = t & 1;
      __syncthreads();  // drains DMA for buf[bi]; all waves done with buf[bi^1]

      if (t + 1 < ntiles) {
        const int nkv0 = kv0 + 64;
        u16* kd = Ks[bi ^ 1];
        u16* vd = Vts[bi ^ 1];
#pragma unroll
        for (int c = 0; c < 2; ++c) {
          const int row = c * 32 + srow;
          const int gc = scc ^ (row & 7);
          async16(kb + (size_t)(nkv0 + row) * QKS + gc * 8, kd + (c * 256 + tid) * 8);
          async16(vtb + (size_t)row * Tn + nkv0 + gc * 8, vd + (c * 256 + tid) * 8);
        }
      }

      // S = Q K^T (already log2-scaled via Q)
      const u16* ks = Ks[bi];
      const u16* vs = Vts[bi];
      f32x4 s[4];
#pragma unroll
      for (int nt = 0; nt < 4; ++nt) s[nt] = (f32x4){0.f, 0.f, 0.f, 0.f};
#pragma unroll
      for (int nt = 0; nt < 4; ++nt) {
        const int rb = nt * 16 + l16;
        ushx8 b0 = *(const ushx8*)(ks + rb * 64 + (quad ^ (rb & 7)) * 8);
        ushx8 b1 = *(const ushx8*)(ks + rb * 64 + ((quad + 4) ^ (rb & 7)) * 8);
        s[nt] = mfma_bf16(qf[0], b0, s[nt]);
        s[nt] = mfma_bf16(qf[1], b1, s[nt]);
      }

      // online softmax (log2 domain), DPP reductions, raw v_exp_f32
      const bool dz = (kv0 + 64 > q0 + wv * 16);
#pragma unroll
      for (int i = 0; i < 4; ++i) {
        const int qr = q0 + wv * 16 + quad * 4 + i;
        float vv[4];
        float rmax = -__builtin_inff();
#pragma unroll
        for (int nt = 0; nt < 4; ++nt) {
          float v = s[nt][i];
          if (dz && (kv0 + nt * 16 + l16) > qr) v = -__builtin_inff();
          vv[nt] = v;
          rmax = fmaxf(rmax, v);
        }
        rmax = red16max(rmax);
        const float mnew = fmaxf(mrow[i], rmax);
        const float al = __builtin_amdgcn_exp2f(mrow[i] - mnew);
        mrow[i] = mnew;
        float rsum = 0.f;
#pragma unroll
        for (int nt = 0; nt < 4; ++nt) {
          float p = __builtin_amdgcn_exp2f(vv[nt] - mnew);
          rsum += p;
          pswv[(quad * 4 + i) * 72 + nt * 16 + l16] = f2bf_rna(p);
        }
        rsum = red16sum(rsum);
        lrow[i] = lrow[i] * al + rsum;
#pragma unroll
        for (int nt = 0; nt < 4; ++nt) o[nt][i] *= al;
      }

      // P A-fragments from wave-local LDS (DS in-order per wave, no barrier)
      ushx8 pf0, pf1;
      {
        const u16* pp = pswv + l16 * 72 + quad * 8;
        pf0 = *(const ushx8*)pp;
        pf1 = *(const ushx8*)(pp + 32);
      }

      // O += P V
#pragma unroll
      for (int nt = 0; nt < 4; ++nt) {
        const int rb = nt * 16 + l16;
        ushx8 v0 = *(const ushx8*)(vs + rb * 64 + (quad ^ (rb & 7)) * 8);
        ushx8 v1 = *(const ushx8*)(vs + rb * 64 + ((quad + 4) ^ (rb & 7)) * 8);
        o[nt] = mfma_bf16(pf0, v0, o[nt]);
        o[nt] = mfma_bf16(pf1, v1, o[nt]);
      }
    }

    // O/l, write y_attn as (B,T,C) bf16
#pragma unroll
    for (int i = 0; i < 4; ++i) {
      const float inv = 1.f / lrow[i];
      const int t = q0 + wv * 16 + quad * 4 + i;
      u16* op = out + ((size_t)(b * Tn + t)) * Cn + h * Dn + l16;
#pragma unroll
      for (int nt = 0; nt < 4; ++nt) op[nt * 16] = f2bf(o[nt][i] * inv);
    }
  }
}

// ---------------- launch ----------------
extern "C" void kernel_launch(void* const* d_in, const int* in_sizes, int n_in,
                              void* d_out, int out_size, void* d_ws, size_t ws_size,
                              hipStream_t stream) {
  const float* x = (const float*)d_in[0];
  const float* w_qkv = (const float*)d_in[1];
  const float* w_proj = (const float*)d_in[2];
  const float* b_proj = (const float*)d_in[3];
  float* out = (float*)d_out;
  char* ws = (char*)d_ws;

  u16* xb     = (u16*)(ws);                 // 16 MiB @ 0
  u16* wqkvb  = (u16*)(ws + 16777216);      //  6 MiB @ 16
  u16* wprojb = (u16*)(ws + 23068672);      //  2 MiB @ 22
  u16* qkb    = (u16*)(ws + 25165824);      // 32 MiB @ 24  (packed QK, stride 2048)
  u16* vtb    = (u16*)(ws + 58720256);      // 16 MiB @ 56
  u16* yb     = (u16*)(ws + 75497472);      // 16 MiB @ 72  (ends 88 MiB)

  cast3_kernel<<<12288, 256, 0, stream>>>(x, xb, 2097152,
                                          w_qkv, wqkvb, 786432,
                                          w_proj, wprojb, 262144);

  gemm_bt<1><<<dim3(Mn / 128, NQKV / 128), 256, 0, stream>>>(
      xb, wqkvb, (void*)qkb, vtb, nullptr, NQKV, Cn);

  attn_kernel<<<dim3(8, Hn, Bn), 256, 0, stream>>>(qkb, vtb, yb);

  gemm_bt<0><<<dim3(Mn / 128, Cn / 128), 256, 0, stream>>>(
      yb, wprojb, (void*)out, nullptr, b_proj, Cn, Cn);
}

// Round 9
// 229.506 us; speedup vs baseline: 1.1370x; 1.0872x over previous
//
#include <hip/hip_runtime.h>
#include <stdint.h>

// MHA forward, B=8 T=1024 C=1024 H=16 D=64.
// cast3 -> QKV GEMM (round-6 structure: 128x128, single-buf LDS, bounds(256,4);
// writes packed QK [stride 2048, Q pre-scaled] + V^T directly)
// -> flash attention (512-thr blocks, 128-row q-tile pairs, peeled causal mask,
// deferred l-reduction) -> proj GEMM (+bias, fp32). 4 launches.

#define Bn 8
#define Tn 1024
#define Cn 1024
#define Hn 16
#define Dn 64
#define Mn (Bn * Tn)      // 8192
#define NQKV (3 * Cn)     // 3072
#define QKS 2048          // packed QK row stride

typedef unsigned short u16;
typedef float f32x4 __attribute__((ext_vector_type(4)));
typedef __bf16 bf16x8 __attribute__((ext_vector_type(8)));
typedef unsigned short ushx8 __attribute__((ext_vector_type(8)));
typedef unsigned short ushx4 __attribute__((ext_vector_type(4)));

__device__ __forceinline__ u16 f2bf(float f) {
  unsigned int u = __float_as_uint(f);
  u += 0x7fffu + ((u >> 16) & 1u);   // RTN-even
  return (u16)(u >> 16);
}
__device__ __forceinline__ u16 f2bf_rna(float f) {
  return (u16)((__float_as_uint(f) + 0x8000u) >> 16);
}

__device__ __forceinline__ f32x4 mfma_bf16(ushx8 a, ushx8 b, f32x4 c) {
  return __builtin_amdgcn_mfma_f32_16x16x32_bf16(
      __builtin_bit_cast(bf16x8, a), __builtin_bit_cast(bf16x8, b), c, 0, 0, 0);
}

// async global->LDS, 16B per lane; LDS dest = wave-uniform base + lane*16 (m104)
__device__ __forceinline__ void async16(const u16* g, u16* l) {
  __builtin_amdgcn_global_load_lds(
      (__attribute__((address_space(1))) void*)(void*)g,
      (__attribute__((address_space(3))) void*)l, 16, 0, 0);
}

// ---- DPP 16-lane butterfly reductions (VALU-rate, no LDS pipe) ----
template <int CTRL>
__device__ __forceinline__ float dppmov(float v) {
  return __builtin_bit_cast(float, __builtin_amdgcn_update_dpp(
      0, __builtin_bit_cast(int, v), CTRL, 0xf, 0xf, true));
}
__device__ __forceinline__ float red16max(float v) {
  v = fmaxf(v, dppmov<0xB1>(v));
  v = fmaxf(v, dppmov<0x4E>(v));
  v = fmaxf(v, dppmov<0x141>(v));
  v = fmaxf(v, dppmov<0x140>(v));
  return v;
}
__device__ __forceinline__ float red16sum(float v) {
  v += dppmov<0xB1>(v);
  v += dppmov<0x4E>(v);
  v += dppmov<0x141>(v);
  v += dppmov<0x140>(v);
  return v;
}

// ---------------- fused cast fp32 -> bf16 (3 tensors, 1 launch) ----------------
__global__ void cast3_kernel(const float* __restrict__ a, u16* __restrict__ oa, int na4,
                             const float* __restrict__ b, u16* __restrict__ ob, int nb4,
                             const float* __restrict__ c, u16* __restrict__ oc, int nc4) {
  int i = blockIdx.x * blockDim.x + threadIdx.x;
  const float* in;
  u16* out;
  if (i < na4) { in = a; out = oa; }
  else if (i < na4 + nb4) { in = b; out = ob; i -= na4; }
  else if (i < na4 + nb4 + nc4) { in = c; out = oc; i -= na4 + nb4; }
  else return;
  float4 v = ((const float4*)in)[i];
  ushx4 o = { f2bf(v.x), f2bf(v.y), f2bf(v.z), f2bf(v.w) };
  ((ushx4*)out)[i] = o;
}

// ---------------- GEMM (round-6 known-best structure) ----------------
// 128x128 block, 2x2 waves, BK=32, single-buffered LDS staging via async DMA.
// QKV=1: cols [0,2048)->packed QK (stride 2048, Q cols scaled); [2048,3072)->V^T.
// QKV=0: fp32 out + bias.
#define SLOG2E 0.18033688011112042f
template <int QKV>
__global__ __launch_bounds__(256, 4) void gemm_bt(
    const u16* __restrict__ A, const u16* __restrict__ Bw,
    void* __restrict__ Cout, u16* __restrict__ vt,
    const float* __restrict__ bias, int N, int K) {
  __shared__ alignas(16) u16 As[128 * 32];
  __shared__ alignas(16) u16 Bs[128 * 32];

  const int tid = threadIdx.x;
  const int lane = tid & 63;
  const int wv = tid >> 6;
  const int quad = lane >> 4;
  const int l16 = lane & 15;
  const int m0 = blockIdx.x * 128;
  const int n0 = blockIdx.y * 128;
  const int wm = (wv >> 1) * 64;
  const int wn = (wv & 1) * 64;

  f32x4 acc[4][4];
#pragma unroll
  for (int i = 0; i < 4; ++i)
#pragma unroll
    for (int j = 0; j < 4; ++j) acc[i][j] = (f32x4){0.f, 0.f, 0.f, 0.f};

  const int r0 = tid >> 2;
  const int cc0 = tid & 3;
  const int gkc0 = cc0 ^ ((r0 >> 1) & 3);
  const int r1 = r0 + 64;
  const int gkc1 = cc0 ^ ((r1 >> 1) & 3);
  const u16* gA0 = A + (size_t)(m0 + r0) * K + gkc0 * 8;
  const u16* gA1 = A + (size_t)(m0 + r1) * K + gkc1 * 8;
  const u16* gB0 = Bw + (size_t)(n0 + r0) * K + gkc0 * 8;
  const u16* gB1 = Bw + (size_t)(n0 + r1) * K + gkc1 * 8;
  u16* lA0 = As + tid * 8;
  u16* lA1 = As + (256 + tid) * 8;
  u16* lB0 = Bs + tid * 8;
  u16* lB1 = Bs + (256 + tid) * 8;

  const u16* pa[4];
  const u16* pb[4];
#pragma unroll
  for (int mi = 0; mi < 4; ++mi) {
    int ra = wm + mi * 16 + l16;
    pa[mi] = As + ra * 32 + (quad ^ ((ra >> 1) & 3)) * 8;
    int rb = wn + mi * 16 + l16;
    pb[mi] = Bs + rb * 32 + (quad ^ ((rb >> 1) & 3)) * 8;
  }

  for (int k0 = 0; k0 < K; k0 += 32) {
    async16(gA0 + k0, lA0);
    async16(gA1 + k0, lA1);
    async16(gB0 + k0, lB0);
    async16(gB1 + k0, lB1);
    __syncthreads();
    ushx8 af[4], bf[4];
#pragma unroll
    for (int i = 0; i < 4; ++i) {
      af[i] = *(const ushx8*)pa[i];
      bf[i] = *(const ushx8*)pb[i];
    }
#pragma unroll
    for (int mi = 0; mi < 4; ++mi)
#pragma unroll
      for (int ni = 0; ni < 4; ++ni)
        acc[mi][ni] = mfma_bf16(af[mi], bf[ni], acc[mi][ni]);
    __syncthreads();
  }

  if constexpr (QKV) {
    if (n0 < 2 * Cn) {
      const float sc = (n0 < Cn) ? SLOG2E : 1.f;
#pragma unroll
      for (int mi = 0; mi < 4; ++mi) {
#pragma unroll
        for (int ni = 0; ni < 4; ++ni) {
          int col = n0 + wn + ni * 16 + l16;
#pragma unroll
          for (int i = 0; i < 4; ++i) {
            int row = m0 + wm + mi * 16 + quad * 4 + i;
            ((u16*)Cout)[(size_t)row * QKS + col] = f2bf(acc[mi][ni][i] * sc);
          }
        }
      }
    } else {
      // V^T: lane's regs i=0..3 are consecutive t -> one 8B packed store
#pragma unroll
      for (int mi = 0; mi < 4; ++mi) {
#pragma unroll
        for (int ni = 0; ni < 4; ++ni) {
          int colV = n0 + wn + ni * 16 + l16 - 2 * Cn;  // 0..1023
          int hh = colV >> 6, dd = colV & 63;
          int row0 = m0 + wm + mi * 16 + quad * 4;
          int bb = row0 >> 10, tt = row0 & 1023;
          unsigned int lo = (unsigned int)f2bf(acc[mi][ni][0]) |
                            ((unsigned int)f2bf(acc[mi][ni][1]) << 16);
          unsigned int hi = (unsigned int)f2bf(acc[mi][ni][2]) |
                            ((unsigned int)f2bf(acc[mi][ni][3]) << 16);
          uint2 pk = {lo, hi};
          *(uint2*)&vt[((size_t)(bb * Hn + hh) * Dn + dd) * Tn + tt] = pk;
        }
      }
    }
  } else {
#pragma unroll
    for (int mi = 0; mi < 4; ++mi) {
#pragma unroll
      for (int ni = 0; ni < 4; ++ni) {
        int col = n0 + wn + ni * 16 + l16;
        float bv = bias[col];
#pragma unroll
        for (int i = 0; i < 4; ++i) {
          int row = m0 + wm + mi * 16 + quad * 4 + i;
          ((float*)Cout)[(size_t)row * N + col] = acc[mi][ni][i] + bv;
        }
      }
    }
  }
}

// ---------------- flash attention v5 ----------------
// 512 blocks (4,16,8) x 512 threads (8 waves). Block j does 128-row q-tiles
// j and 7-j (18 kv-tiles total — perfectly balanced, 2 blocks/CU = 16 waves/CU,
// no tail). Wave wv owns q rows [wv*16, wv*16+16) of the tile. Per wave exactly
// one diagonal kv-tile (tdiag = q0w>>6): earlier tiles unmasked, later skipped.
// Double-buffered async K/V^T staging; DPP reductions; raw v_exp_f32;
// per-lane l partials reduced once per phase. QK stride 2048, Q pre-scaled.
__global__ __launch_bounds__(512, 4) void attn_kernel(
    const u16* __restrict__ qk, const u16* __restrict__ vt,
    u16* __restrict__ out) {
  const int j = blockIdx.x, h = blockIdx.y, b = blockIdx.z;
  const int tid = threadIdx.x;
  const int lane = tid & 63;
  const int wv = tid >> 6;           // 0..7
  const int quad = lane >> 4;
  const int l16 = lane & 15;

  __shared__ alignas(16) u16 Ks[2][64 * 64];   // [buf][kv][d] XOR-swizzled
  __shared__ alignas(16) u16 Vts[2][64 * 64];  // [buf][d][kv] XOR-swizzled
  __shared__ alignas(16) u16 Ps[8][16 * 72];   // per-wave P

  const u16* qb = qk + (size_t)b * Tn * QKS + h * Dn;
  const u16* kb = qk + (size_t)b * Tn * QKS + Cn + h * Dn;
  const u16* vtb = vt + (size_t)(b * Hn + h) * Dn * Tn;

  const int srow = tid >> 3;  // 0..63
  const int scc = tid & 7;
  const int sgc = scc ^ (srow & 7);
  u16* pswv = Ps[wv];

#pragma unroll 1
  for (int ph = 0; ph < 2; ++ph) {
    const int qt = ph ? (7 - j) : j;
    const int q0w = qt * 128 + wv * 16;   // this wave's first q row
    const int ntiles = 2 * qt + 2;
    const int tdiag = q0w >> 6;           // in-phase diagonal tile index

    // Q fragments (A-operand: m=l16, k=quad*8+jj); already scaled by SLOG2E
    ushx8 qf[2];
    {
      const u16* qp = qb + (size_t)(q0w + l16) * QKS + quad * 8;
      qf[0] = *(const ushx8*)qp;
      qf[1] = *(const ushx8*)(qp + 32);
    }

    f32x4 o[4];
#pragma unroll
    for (int nt = 0; nt < 4; ++nt) o[nt] = (f32x4){0.f, 0.f, 0.f, 0.f};
    float mrow[4], lrow[4];
#pragma unroll
    for (int i = 0; i < 4; ++i) { mrow[i] = -__builtin_inff(); lrow[i] = 0.f; }

    __syncthreads();  // previous phase's compute done before overwriting buf0

    // prefetch tile 0 -> buf 0 (one 16B DMA per thread per buffer)
    async16(kb + (size_t)srow * QKS + sgc * 8, Ks[0] + tid * 8);
    async16(vtb + (size_t)srow * Tn + sgc * 8, Vts[0] + tid * 8);

#pragma unroll 1
    for (int t = 0; t < ntiles; ++t) {
      const int kv0 = t * 64;
      const int bi = t & 1;
      __syncthreads();  // drains DMA for buf[bi]; all waves done with buf[bi^1]

      if (t + 1 < ntiles) {
        const int nkv0 = kv0 + 64;
        async16(kb + (size_t)(nkv0 + srow) * QKS + sgc * 8, Ks[bi ^ 1] + tid * 8);
        async16(vtb + (size_t)srow * Tn + nkv0 + sgc * 8, Vts[bi ^ 1] + tid * 8);
      }

      if (t > tdiag) continue;   // fully-masked for this wave (wave-uniform)

      // S = Q K^T (already log2-scaled via Q)
      const u16* ks = Ks[bi];
      const u16* vs = Vts[bi];
      f32x4 s[4];
#pragma unroll
      for (int nt = 0; nt < 4; ++nt) s[nt] = (f32x4){0.f, 0.f, 0.f, 0.f};
#pragma unroll
      for (int nt = 0; nt < 4; ++nt) {
        const int rb = nt * 16 + l16;
        ushx8 b0 = *(const ushx8*)(ks + rb * 64 + (quad ^ (rb & 7)) * 8);
        ushx8 b1 = *(const ushx8*)(ks + rb * 64 + ((quad + 4) ^ (rb & 7)) * 8);
        s[nt] = mfma_bf16(qf[0], b0, s[nt]);
        s[nt] = mfma_bf16(qf[1], b1, s[nt]);
      }

      // online softmax; mask only on the wave's single diagonal tile
      if (t == tdiag) {
#pragma unroll
        for (int i = 0; i < 4; ++i) {
          const int qr = q0w + quad * 4 + i;
          float vv[4];
          float rmax = -__builtin_inff();
#pragma unroll
          for (int nt = 0; nt < 4; ++nt) {
            float v = s[nt][i];
            if ((kv0 + nt * 16 + l16) > qr) v = -__builtin_inff();
            vv[nt] = v;
            rmax = fmaxf(rmax, v);
          }
          rmax = red16max(rmax);
          const float mnew = fmaxf(mrow[i], rmax);
          const float al = __builtin_amdgcn_exp2f(mrow[i] - mnew);
          mrow[i] = mnew;
          float rsum = 0.f;
#pragma unroll
          for (int nt = 0; nt < 4; ++nt) {
            float p = __builtin_amdgcn_exp2f(vv[nt] - mnew);
            rsum += p;
            pswv[(quad * 4 + i) * 72 + nt * 16 + l16] = f2bf_rna(p);
          }
          lrow[i] = lrow[i] * al + rsum;   // per-lane partial; reduced at end
#pragma unroll
          for (int nt = 0; nt < 4; ++nt) o[nt][i] *= al;
        }
      } else {
#pragma unroll
        for (int i = 0; i < 4; ++i) {
          float rmax = fmaxf(fmaxf(s[0][i], s[1][i]), fmaxf(s[2][i], s[3][i]));
          rmax = red16max(rmax);
          const float mnew = fmaxf(mrow[i], rmax);
          const float al = __builtin_amdgcn_exp2f(mrow[i] - mnew);
          mrow[i] = mnew;
          float rsum = 0.f;
#pragma unroll
          for (int nt = 0; nt < 4; ++nt) {
            float p = __builtin_amdgcn_exp2f(s[nt][i] - mnew);
            rsum += p;
            pswv[(quad * 4 + i) * 72 + nt * 16 + l16] = f2bf_rna(p);
          }
          lrow[i] = lrow[i] * al + rsum;
#pragma unroll
          for (int nt = 0; nt < 4; ++nt) o[nt][i] *= al;
        }
      }

      // P A-fragments from wave-local LDS (DS in-order per wave, no barrier)
      ushx8 pf0, pf1;
      {
        const u16* pp = pswv + l16 * 72 + quad * 8;
        pf0 = *(const ushx8*)pp;
        pf1 = *(const ushx8*)(pp + 32);
      }

      // O += P V
#pragma unroll
      for (int nt = 0; nt < 4; ++nt) {
        const int rb = nt * 16 + l16;
        ushx8 v0 = *(const ushx8*)(vs + rb * 64 + (quad ^ (rb & 7)) * 8);
        ushx8 v1 = *(const ushx8*)(vs + rb * 64 + ((quad + 4) ^ (rb & 7)) * 8);
        o[nt] = mfma_bf16(pf0, v0, o[nt]);
        o[nt] = mfma_bf16(pf1, v1, o[nt]);
      }
    }

    // O/l (16-lane l reduction deferred to here), write y_attn bf16
#pragma unroll
    for (int i = 0; i < 4; ++i) {
      const float inv = 1.f / red16sum(lrow[i]);
      const int trow = q0w + quad * 4 + i;
      u16* op = out + ((size_t)(b * Tn + trow)) * Cn + h * Dn + l16;
#pragma unroll
      for (int nt = 0; nt < 4; ++nt) op[nt * 16] = f2bf(o[nt][i] * inv);
    }
  }
}

// ---------------- launch ----------------
extern "C" void kernel_launch(void* const* d_in, const int* in_sizes, int n_in,
                              void* d_out, int out_size, void* d_ws, size_t ws_size,
                              hipStream_t stream) {
  const float* x = (const float*)d_in[0];
  const float* w_qkv = (const float*)d_in[1];
  const float* w_proj = (const float*)d_in[2];
  const float* b_proj = (const float*)d_in[3];
  float* out = (float*)d_out;
  char* ws = (char*)d_ws;

  u16* xb     = (u16*)(ws);                 // 16 MiB @ 0
  u16* wqkvb  = (u16*)(ws + 16777216);      //  6 MiB @ 16
  u16* wprojb = (u16*)(ws + 23068672);      //  2 MiB @ 22
  u16* qkb    = (u16*)(ws + 25165824);      // 32 MiB @ 24  (packed QK, stride 2048)
  u16* vtb    = (u16*)(ws + 58720256);      // 16 MiB @ 56
  u16* yb     = (u16*)(ws + 75497472);      // 16 MiB @ 72  (ends 88 MiB)

  cast3_kernel<<<12288, 256, 0, stream>>>(x, xb, 2097152,
                                          w_qkv, wqkvb, 786432,
                                          w_proj, wprojb, 262144);

  gemm_bt<1><<<dim3(Mn / 128, NQKV / 128), 256, 0, stream>>>(
      xb, wqkvb, (void*)qkb, vtb, nullptr, NQKV, Cn);

  attn_kernel<<<dim3(4, Hn, Bn), 512, 0, stream>>>(qkb, vtb, yb);

  gemm_bt<0><<<dim3(Mn / 128, Cn / 128), 256, 0, stream>>>(
      yb, wprojb, (void*)out, nullptr, b_proj, Cn, Cn);
}